// Round 1
// baseline (241.375 us; speedup 1.0000x reference)
//
#include <hip/hip_runtime.h>
#include <hip/hip_bf16.h>

typedef __attribute__((ext_vector_type(8))) short bf16x8;
typedef __attribute__((ext_vector_type(4))) float f32x4;

__device__ __forceinline__ void gload_lds16(const void* g, void* l) {
    __builtin_amdgcn_global_load_lds(
        (const __attribute__((address_space(1))) unsigned int*)g,
        (__attribute__((address_space(3))) unsigned int*)l, 16, 0, 0);
}

// ---------------- fp32 -> bf16 elementwise convert (8 elems/thread) ----------------
__global__ void k_cvt_bf16(const float* __restrict__ x, __hip_bfloat16* __restrict__ o, int n8) {
    int i = blockIdx.x * 256 + threadIdx.x;
    if (i >= n8) return;
    const float4* xp = (const float4*)(x + (size_t)i * 8);
    float4 a = xp[0], b = xp[1];
    union { __hip_bfloat16 h[8]; uint4 u; } tu;
    tu.h[0] = __float2bfloat16(a.x); tu.h[1] = __float2bfloat16(a.y);
    tu.h[2] = __float2bfloat16(a.z); tu.h[3] = __float2bfloat16(a.w);
    tu.h[4] = __float2bfloat16(b.x); tu.h[5] = __float2bfloat16(b.y);
    tu.h[6] = __float2bfloat16(b.z); tu.h[7] = __float2bfloat16(b.w);
    *(uint4*)(o + (size_t)i * 8) = tu.u;
}

// ---------------- transpose fp32 [K][N] -> bf16 [N][K] ----------------
__global__ void k_tr(const float* __restrict__ src, __hip_bfloat16* __restrict__ dst, int K, int N) {
    __shared__ float tile[32][33];
    int n0 = blockIdx.x * 32, k0 = blockIdx.y * 32;
    int tx = threadIdx.x & 31, ty = threadIdx.x >> 5;
#pragma unroll
    for (int i = 0; i < 4; i++)
        tile[ty + i * 8][tx] = src[(size_t)(k0 + ty + i * 8) * N + n0 + tx];
    __syncthreads();
#pragma unroll
    for (int i = 0; i < 4; i++)
        dst[(size_t)(n0 + ty + i * 8) * K + k0 + tx] = __float2bfloat16(tile[tx][ty + i * 8]);
}

// ---------------- bf16 GEMM: C[M][N] = A[M][K] * Bt[N][K]^T, 128x128 tile ----------------
// EPI=0: QKV epilogue (bias, scale q, scatter to q/k/v buffers; N=3072)
// EPI=1: out = val + bias, fp32 [M][N]
#define QSCALE 0.18033688011111204f  /* (1/8) * log2(e) */

template <int EPI>
__global__ __launch_bounds__(256, 2) void k_gemm(
    const __hip_bfloat16* __restrict__ A, const __hip_bfloat16* __restrict__ Bt,
    int M, int N, int K,
    const float* __restrict__ b0, const float* __restrict__ b1, const float* __restrict__ b2,
    __hip_bfloat16* __restrict__ qb, __hip_bfloat16* __restrict__ kb, __hip_bfloat16* __restrict__ vb,
    float* __restrict__ outp)
{
    __shared__ __align__(16) __hip_bfloat16 As[128 * 64];
    __shared__ __align__(16) __hip_bfloat16 Bs[128 * 64];
    const int t = threadIdx.x;
    const int lane = t & 63, w = t >> 6;
    const int wr = w >> 1, wc = w & 1;
    const int r16 = lane & 15, kg = lane >> 4;
    const int m0 = blockIdx.x * 128, n0 = blockIdx.y * 128;
    f32x4 acc[4][4] = {};
    const int ksteps = K >> 6;
    for (int kt = 0; kt < ksteps; ++kt) {
        if (kt) __syncthreads();
        const int ks = kt * 64;
#pragma unroll
        for (int i = 0; i < 4; i++) {
            int ci = i * 256 + t;
            int row = ci >> 3, kc = (ci & 7) * 8;
            gload_lds16(A + (size_t)(m0 + row) * K + ks + kc, As + ci * 8);
        }
#pragma unroll
        for (int i = 0; i < 4; i++) {
            int ci = i * 256 + t;
            int row = ci >> 3, kc = (ci & 7) * 8;
            gload_lds16(Bt + (size_t)(n0 + row) * K + ks + kc, Bs + ci * 8);
        }
        __syncthreads();
#pragma unroll
        for (int c = 0; c < 2; c++) {
            bf16x8 af[4], bfr[4];
#pragma unroll
            for (int mi = 0; mi < 4; mi++)
                af[mi] = *(const bf16x8*)(As + (wr * 64 + mi * 16 + r16) * 64 + c * 32 + kg * 8);
#pragma unroll
            for (int ni = 0; ni < 4; ni++)
                bfr[ni] = *(const bf16x8*)(Bs + (wc * 64 + ni * 16 + r16) * 64 + c * 32 + kg * 8);
#pragma unroll
            for (int mi = 0; mi < 4; mi++)
#pragma unroll
                for (int ni = 0; ni < 4; ni++)
                    acc[mi][ni] = __builtin_amdgcn_mfma_f32_16x16x32_bf16(af[mi], bfr[ni], acc[mi][ni], 0, 0, 0);
        }
    }
    // epilogue: C row = kg*4+j, col = r16 (per 16x16 fragment)
#pragma unroll
    for (int mi = 0; mi < 4; mi++) {
#pragma unroll
        for (int ni = 0; ni < 4; ni++) {
#pragma unroll
            for (int j = 0; j < 4; j++) {
                int m = m0 + wr * 64 + mi * 16 + kg * 4 + j;
                int n = n0 + wc * 64 + ni * 16 + r16;
                float val = acc[mi][ni][j];
                if (EPI == 0) {
                    int proj = n >> 10, r = n & 1023;
                    int hh = r >> 6, dd = r & 63;
                    int bb = m >> 11, tt = m & 2047;
                    if (proj == 0) {
                        val = (val + b0[r]) * QSCALE;
                        qb[((size_t)(bb * 16 + hh) * 2048 + tt) * 64 + dd] = __float2bfloat16(val);
                    } else if (proj == 1) {
                        val += b1[r];
                        kb[((size_t)(bb * 16 + hh) * 2048 + tt) * 64 + dd] = __float2bfloat16(val);
                    } else {
                        val += b2[r];
                        vb[((size_t)(bb * 16 + hh) * 64 + dd) * 2048 + tt] = __float2bfloat16(val);
                    }
                } else {
                    outp[(size_t)m * N + n] = val + b0[n];
                }
            }
        }
    }
}

// ---------------- flash attention: block = (64 q-rows, one bh), 4 waves x 16 rows ----------------
__global__ __launch_bounds__(256, 2) void k_attn(
    const __hip_bfloat16* __restrict__ qbuf,
    const __hip_bfloat16* __restrict__ kbuf,
    const __hip_bfloat16* __restrict__ vtbuf,
    __hip_bfloat16* __restrict__ y)
{
    __shared__ __align__(16) __hip_bfloat16 Kl[64 * 64];
    __shared__ __align__(16) __hip_bfloat16 Vl[64 * 64];
    __shared__ __align__(16) __hip_bfloat16 Pl[4 * 16 * 64];
    const int t = threadIdx.x, lane = t & 63, w = t >> 6;
    const int r16 = lane & 15, kg = lane >> 4;
    const int bh = blockIdx.y;
    const int qt = blockIdx.x;
    const int q0 = qt * 64 + w * 16;
    const __hip_bfloat16* qp = qbuf + ((size_t)bh * 2048 + q0) * 64;
    bf16x8 qf0 = *(const bf16x8*)(qp + r16 * 64 + kg * 8);
    bf16x8 qf1 = *(const bf16x8*)(qp + r16 * 64 + 32 + kg * 8);
    f32x4 O[4] = {};
    float mrow[4], lrow[4];
#pragma unroll
    for (int j = 0; j < 4; j++) { mrow[j] = -3.0e38f; lrow[j] = 0.f; }
    const __hip_bfloat16* kb = kbuf + (size_t)bh * 2048 * 64;
    const __hip_bfloat16* vb = vtbuf + (size_t)bh * 64 * 2048;
    __hip_bfloat16* pw = Pl + w * 16 * 64;
    for (int kt = 0; kt <= qt; ++kt) {
        if (kt) __syncthreads();
#pragma unroll
        for (int i = 0; i < 2; i++) {
            int ci = i * 256 + t;
            gload_lds16(kb + (size_t)kt * 4096 + ci * 8, Kl + ci * 8);
        }
#pragma unroll
        for (int i = 0; i < 2; i++) {
            int ci = i * 256 + t;
            int row = ci >> 3, c8 = (ci & 7) * 8;
            gload_lds16(vb + (size_t)row * 2048 + kt * 64 + c8, Vl + ci * 8);
        }
        __syncthreads();
        f32x4 S[4];
#pragma unroll
        for (int ct = 0; ct < 4; ct++) {
            f32x4 s = {};
            bf16x8 kf0 = *(const bf16x8*)(Kl + (ct * 16 + r16) * 64 + kg * 8);
            s = __builtin_amdgcn_mfma_f32_16x16x32_bf16(qf0, kf0, s, 0, 0, 0);
            bf16x8 kf1 = *(const bf16x8*)(Kl + (ct * 16 + r16) * 64 + 32 + kg * 8);
            s = __builtin_amdgcn_mfma_f32_16x16x32_bf16(qf1, kf1, s, 0, 0, 0);
            S[ct] = s;
        }
        if (kt == qt) {  // diagonal tile: causal mask
#pragma unroll
            for (int ct = 0; ct < 4; ct++)
#pragma unroll
                for (int j = 0; j < 4; j++)
                    if (ct * 16 + r16 > w * 16 + kg * 4 + j) S[ct][j] = -3.0e38f;
        }
        float rmax[4], rsum[4], alpha[4];
#pragma unroll
        for (int j = 0; j < 4; j++)
            rmax[j] = fmaxf(fmaxf(S[0][j], S[1][j]), fmaxf(S[2][j], S[3][j]));
#pragma unroll
        for (int j = 0; j < 4; j++) {
            rmax[j] = fmaxf(rmax[j], __shfl_xor(rmax[j], 1));
            rmax[j] = fmaxf(rmax[j], __shfl_xor(rmax[j], 2));
            rmax[j] = fmaxf(rmax[j], __shfl_xor(rmax[j], 4));
            rmax[j] = fmaxf(rmax[j], __shfl_xor(rmax[j], 8));
        }
#pragma unroll
        for (int j = 0; j < 4; j++) {
            float mn = fmaxf(mrow[j], rmax[j]);
            alpha[j] = exp2f(mrow[j] - mn);
            mrow[j] = mn;
        }
#pragma unroll
        for (int ct = 0; ct < 4; ct++)
#pragma unroll
            for (int j = 0; j < 4; j++)
                S[ct][j] = exp2f(S[ct][j] - mrow[j]);
#pragma unroll
        for (int j = 0; j < 4; j++) {
            rsum[j] = S[0][j] + S[1][j] + S[2][j] + S[3][j];
            rsum[j] += __shfl_xor(rsum[j], 1);
            rsum[j] += __shfl_xor(rsum[j], 2);
            rsum[j] += __shfl_xor(rsum[j], 4);
            rsum[j] += __shfl_xor(rsum[j], 8);
            lrow[j] = lrow[j] * alpha[j] + rsum[j];
        }
        // P -> per-wave LDS (C-layout -> A-layout round trip)
#pragma unroll
        for (int ct = 0; ct < 4; ct++)
#pragma unroll
            for (int j = 0; j < 4; j++)
                pw[(kg * 4 + j) * 64 + ct * 16 + r16] = __float2bfloat16(S[ct][j]);
#pragma unroll
        for (int ot = 0; ot < 4; ot++)
#pragma unroll
            for (int j = 0; j < 4; j++)
                O[ot][j] *= alpha[j];
#pragma unroll
        for (int ot = 0; ot < 4; ot++) {
#pragma unroll
            for (int c = 0; c < 2; c++) {
                bf16x8 pa = *(const bf16x8*)(pw + r16 * 64 + c * 32 + kg * 8);
                bf16x8 vf = *(const bf16x8*)(Vl + (ot * 16 + r16) * 64 + c * 32 + kg * 8);
                O[ot] = __builtin_amdgcn_mfma_f32_16x16x32_bf16(pa, vf, O[ot], 0, 0, 0);
            }
        }
    }
    const int b = bh >> 4, h = bh & 15;
    float inv[4];
#pragma unroll
    for (int j = 0; j < 4; j++) inv[j] = 1.0f / lrow[j];
#pragma unroll
    for (int ot = 0; ot < 4; ot++)
#pragma unroll
        for (int j = 0; j < 4; j++) {
            int qq = qt * 64 + w * 16 + kg * 4 + j;
            y[((size_t)b * 2048 + qq) * 1024 + h * 64 + ot * 16 + r16] = __float2bfloat16(O[ot][j] * inv[j]);
        }
}

extern "C" void kernel_launch(void* const* d_in, const int* in_sizes, int n_in,
                              void* d_out, int out_size, void* d_ws, size_t ws_size,
                              hipStream_t stream) {
    const float* xp = (const float*)d_in[0];
    const float* Wq = (const float*)d_in[1];
    const float* bq = (const float*)d_in[2];
    const float* Wk = (const float*)d_in[3];
    const float* bk = (const float*)d_in[4];
    const float* Wv = (const float*)d_in[5];
    const float* bv = (const float*)d_in[6];
    const float* Wp = (const float*)d_in[7];
    const float* bp = (const float*)d_in[8];
    float* out = (float*)d_out;

    char* ws = (char*)d_ws;
    __hip_bfloat16* xb     = (__hip_bfloat16*)(ws);                  //  4096*1152 bf16
    __hip_bfloat16* Wqkv_t = (__hip_bfloat16*)(ws + 9437184);        //  3072*1152 bf16 (B^T)
    __hip_bfloat16* Wp_t   = (__hip_bfloat16*)(ws + 16515072);       //  1024*1024 bf16 (B^T)
    __hip_bfloat16* qb     = (__hip_bfloat16*)(ws + 18612224);       //  [32][2048][64]
    __hip_bfloat16* kbv    = (__hip_bfloat16*)(ws + 27000832);       //  [32][2048][64]
    __hip_bfloat16* vtb    = (__hip_bfloat16*)(ws + 35389440);       //  [32][64][2048] (V^T)
    __hip_bfloat16* yb     = (__hip_bfloat16*)(ws + 43778048);       //  [4096][1024]

    k_cvt_bf16<<<2304, 256, 0, stream>>>(xp, xb, 589824);
    dim3 trg(1024 / 32, 1152 / 32);
    k_tr<<<trg, 256, 0, stream>>>(Wq, Wqkv_t + (size_t)0 * 1024 * 1152, 1152, 1024);
    k_tr<<<trg, 256, 0, stream>>>(Wk, Wqkv_t + (size_t)1 * 1024 * 1152, 1152, 1024);
    k_tr<<<trg, 256, 0, stream>>>(Wv, Wqkv_t + (size_t)2 * 1024 * 1152, 1152, 1024);
    dim3 trg2(1024 / 32, 1024 / 32);
    k_tr<<<trg2, 256, 0, stream>>>(Wp, Wp_t, 1024, 1024);

    dim3 g1(4096 / 128, 3072 / 128);
    k_gemm<0><<<g1, 256, 0, stream>>>(xb, Wqkv_t, 4096, 3072, 1152, bq, bk, bv, qb, kbv, vtb, nullptr);
    dim3 ga(2048 / 64, 32);
    k_attn<<<ga, 256, 0, stream>>>(qb, kbv, vtb, yb);
    dim3 g2(4096 / 128, 1024 / 128);
    k_gemm<1><<<g2, 256, 0, stream>>>(yb, Wp_t, 4096, 1024, 1024, bp, nullptr, nullptr,
                                      nullptr, nullptr, nullptr, out);
}

// Round 2
// 205.278 us; speedup vs baseline: 1.1758x; 1.1758x over previous
//
#include <hip/hip_runtime.h>
#include <hip/hip_bf16.h>

typedef __attribute__((ext_vector_type(8))) short bf16x8;
typedef __attribute__((ext_vector_type(4))) float f32x4;

__device__ __forceinline__ void gload_lds16(const void* g, void* l) {
    __builtin_amdgcn_global_load_lds(
        (const __attribute__((address_space(1))) unsigned int*)g,
        (__attribute__((address_space(3))) unsigned int*)l, 16, 0, 0);
}

// ---------------- fp32 -> bf16 elementwise convert (8 elems/thread) ----------------
__global__ void k_cvt_bf16(const float* __restrict__ x, __hip_bfloat16* __restrict__ o, int n8) {
    int i = blockIdx.x * 256 + threadIdx.x;
    if (i >= n8) return;
    const float4* xp = (const float4*)(x + (size_t)i * 8);
    float4 a = xp[0], b = xp[1];
    union { __hip_bfloat16 h[8]; uint4 u; } tu;
    tu.h[0] = __float2bfloat16(a.x); tu.h[1] = __float2bfloat16(a.y);
    tu.h[2] = __float2bfloat16(a.z); tu.h[3] = __float2bfloat16(a.w);
    tu.h[4] = __float2bfloat16(b.x); tu.h[5] = __float2bfloat16(b.y);
    tu.h[6] = __float2bfloat16(b.z); tu.h[7] = __float2bfloat16(b.w);
    *(uint4*)(o + (size_t)i * 8) = tu.u;
}

// ---------------- transpose fp32 [K][N] -> bf16 [N][K] ----------------
__global__ void k_tr(const float* __restrict__ src, __hip_bfloat16* __restrict__ dst, int K, int N) {
    __shared__ float tile[32][33];
    int n0 = blockIdx.x * 32, k0 = blockIdx.y * 32;
    int tx = threadIdx.x & 31, ty = threadIdx.x >> 5;
#pragma unroll
    for (int i = 0; i < 4; i++)
        tile[ty + i * 8][tx] = src[(size_t)(k0 + ty + i * 8) * N + n0 + tx];
    __syncthreads();
#pragma unroll
    for (int i = 0; i < 4; i++)
        dst[(size_t)(n0 + ty + i * 8) * K + k0 + tx] = __float2bfloat16(tile[tx][ty + i * 8]);
}

// ---------------- bf16 GEMM: C[M][N] = A[M][K] * Bt[N][K]^T, 128x128 tile ----------------
#define QSCALE 0.18033688011111204f  /* (1/8) * log2(e) */

template <int EPI>
__global__ __launch_bounds__(256, 2) void k_gemm(
    const __hip_bfloat16* __restrict__ A, const __hip_bfloat16* __restrict__ Bt,
    int M, int N, int K,
    const float* __restrict__ b0, const float* __restrict__ b1, const float* __restrict__ b2,
    __hip_bfloat16* __restrict__ qb, __hip_bfloat16* __restrict__ kb, __hip_bfloat16* __restrict__ vb,
    float* __restrict__ outp)
{
    __shared__ __align__(16) __hip_bfloat16 As[128 * 64];
    __shared__ __align__(16) __hip_bfloat16 Bs[128 * 64];
    const int t = threadIdx.x;
    const int lane = t & 63, w = t >> 6;
    const int wr = w >> 1, wc = w & 1;
    const int r16 = lane & 15, kg = lane >> 4;
    const int m0 = blockIdx.x * 128, n0 = blockIdx.y * 128;
    f32x4 acc[4][4] = {};
    const int ksteps = K >> 6;
    for (int kt = 0; kt < ksteps; ++kt) {
        if (kt) __syncthreads();
        const int ks = kt * 64;
#pragma unroll
        for (int i = 0; i < 4; i++) {
            int ci = i * 256 + t;
            int row = ci >> 3, kc = (ci & 7) * 8;
            gload_lds16(A + (size_t)(m0 + row) * K + ks + kc, As + ci * 8);
        }
#pragma unroll
        for (int i = 0; i < 4; i++) {
            int ci = i * 256 + t;
            int row = ci >> 3, kc = (ci & 7) * 8;
            gload_lds16(Bt + (size_t)(n0 + row) * K + ks + kc, Bs + ci * 8);
        }
        __syncthreads();
#pragma unroll
        for (int c = 0; c < 2; c++) {
            bf16x8 af[4], bfr[4];
#pragma unroll
            for (int mi = 0; mi < 4; mi++)
                af[mi] = *(const bf16x8*)(As + (wr * 64 + mi * 16 + r16) * 64 + c * 32 + kg * 8);
#pragma unroll
            for (int ni = 0; ni < 4; ni++)
                bfr[ni] = *(const bf16x8*)(Bs + (wc * 64 + ni * 16 + r16) * 64 + c * 32 + kg * 8);
#pragma unroll
            for (int mi = 0; mi < 4; mi++)
#pragma unroll
                for (int ni = 0; ni < 4; ni++)
                    acc[mi][ni] = __builtin_amdgcn_mfma_f32_16x16x32_bf16(af[mi], bfr[ni], acc[mi][ni], 0, 0, 0);
        }
    }
#pragma unroll
    for (int mi = 0; mi < 4; mi++) {
#pragma unroll
        for (int ni = 0; ni < 4; ni++) {
#pragma unroll
            for (int j = 0; j < 4; j++) {
                int m = m0 + wr * 64 + mi * 16 + kg * 4 + j;
                int n = n0 + wc * 64 + ni * 16 + r16;
                float val = acc[mi][ni][j];
                if (EPI == 0) {
                    int proj = n >> 10, r = n & 1023;
                    int hh = r >> 6, dd = r & 63;
                    int bb = m >> 11, tt = m & 2047;
                    if (proj == 0) {
                        val = (val + b0[r]) * QSCALE;
                        qb[((size_t)(bb * 16 + hh) * 2048 + tt) * 64 + dd] = __float2bfloat16(val);
                    } else if (proj == 1) {
                        val += b1[r];
                        kb[((size_t)(bb * 16 + hh) * 2048 + tt) * 64 + dd] = __float2bfloat16(val);
                    } else {
                        val += b2[r];
                        vb[((size_t)(bb * 16 + hh) * 64 + dd) * 2048 + tt] = __float2bfloat16(val);
                    }
                } else {
                    outp[(size_t)m * N + n] = val + b0[n];
                }
            }
        }
    }
}

// ---------------- flash attention v2: XOR-swizzled LDS + double-buffered prefetch ----------------
// block = (64 q-rows, one bh), 4 waves x 16 rows; KVBLK=64
// LDS swizzle (T2 / G4): logical (row, col-elem) stored at row*64 + (col ^ ((row&7)<<3)).
// global_load_lds writes linearly -> pre-swizzle the GLOBAL source (rule #21).
__global__ __launch_bounds__(256, 4) void k_attn(
    const __hip_bfloat16* __restrict__ qbuf,
    const __hip_bfloat16* __restrict__ kbuf,
    const __hip_bfloat16* __restrict__ vtbuf,
    __hip_bfloat16* __restrict__ y)
{
    __shared__ __align__(16) __hip_bfloat16 Kl[2][64 * 64];
    __shared__ __align__(16) __hip_bfloat16 Vl[2][64 * 64];
    __shared__ __align__(16) __hip_bfloat16 Pl[4 * 16 * 64];
    const int t = threadIdx.x, lane = t & 63, w = t >> 6;
    const int r16 = lane & 15, kg = lane >> 4;
    const int bh = blockIdx.y;
    const int qt = (int)gridDim.x - 1 - (int)blockIdx.x;  // longest blocks launch first
    const int swr = (r16 & 7) << 3;                       // read-side swizzle XOR (elements)
    const int q0 = qt * 64 + w * 16;
    const __hip_bfloat16* qp = qbuf + ((size_t)bh * 2048 + q0) * 64;
    bf16x8 qf0 = *(const bf16x8*)(qp + r16 * 64 + kg * 8);
    bf16x8 qf1 = *(const bf16x8*)(qp + r16 * 64 + 32 + kg * 8);
    f32x4 O[4] = {};
    float mrow[4], lrow[4];
#pragma unroll
    for (int j = 0; j < 4; j++) { mrow[j] = -3.0e38f; lrow[j] = 0.f; }
    const __hip_bfloat16* kb = kbuf + (size_t)bh * 2048 * 64;
    const __hip_bfloat16* vb = vtbuf + (size_t)bh * 64 * 2048;
    __hip_bfloat16* pw = Pl + w * 16 * 64;

    // staging: 2 chunks x 256 threads x 16B cover one 8KB tile; pre-swizzled source cols
    const int ci0 = t, ci1 = 256 + t;
    const int kr0 = ci0 >> 3, sc0 = ((ci0 & 7) * 8) ^ ((kr0 & 7) << 3);
    const int kr1 = ci1 >> 3, sc1 = ((ci1 & 7) * 8) ^ ((kr1 & 7) << 3);

    // prologue: stage tile 0 into buffer 0
    gload_lds16(kb + (size_t)kr0 * 64 + sc0, &Kl[0][ci0 * 8]);
    gload_lds16(kb + (size_t)kr1 * 64 + sc1, &Kl[0][ci1 * 8]);
    gload_lds16(vb + (size_t)kr0 * 2048 + sc0, &Vl[0][ci0 * 8]);
    gload_lds16(vb + (size_t)kr1 * 2048 + sc1, &Vl[0][ci1 * 8]);
    __syncthreads();

    for (int kt = 0; kt <= qt; ++kt) {
        const int cur = kt & 1;
        // issue next tile's loads first; latency hides under this tile's compute
        if (kt < qt) {
            const int kn = kt + 1;
            gload_lds16(kb + (size_t)kn * 4096 + (size_t)kr0 * 64 + sc0, &Kl[cur ^ 1][ci0 * 8]);
            gload_lds16(kb + (size_t)kn * 4096 + (size_t)kr1 * 64 + sc1, &Kl[cur ^ 1][ci1 * 8]);
            gload_lds16(vb + (size_t)kr0 * 2048 + kn * 64 + sc0, &Vl[cur ^ 1][ci0 * 8]);
            gload_lds16(vb + (size_t)kr1 * 2048 + kn * 64 + sc1, &Vl[cur ^ 1][ci1 * 8]);
        }
        const __hip_bfloat16* Klb = Kl[cur];
        const __hip_bfloat16* Vlb = Vl[cur];
        f32x4 S[4];
#pragma unroll
        for (int ct = 0; ct < 4; ct++) {
            f32x4 s = {};
            const int r = ct * 16 + r16;
            bf16x8 kf0 = *(const bf16x8*)(Klb + r * 64 + ((kg * 8) ^ swr));
            s = __builtin_amdgcn_mfma_f32_16x16x32_bf16(qf0, kf0, s, 0, 0, 0);
            bf16x8 kf1 = *(const bf16x8*)(Klb + r * 64 + ((32 + kg * 8) ^ swr));
            s = __builtin_amdgcn_mfma_f32_16x16x32_bf16(qf1, kf1, s, 0, 0, 0);
            S[ct] = s;
        }
        if (kt == qt) {  // diagonal tile: causal mask
#pragma unroll
            for (int ct = 0; ct < 4; ct++)
#pragma unroll
                for (int j = 0; j < 4; j++)
                    if (ct * 16 + r16 > w * 16 + kg * 4 + j) S[ct][j] = -3.0e38f;
        }
        float rmax[4], rsum[4], alpha[4];
#pragma unroll
        for (int j = 0; j < 4; j++)
            rmax[j] = fmaxf(fmaxf(S[0][j], S[1][j]), fmaxf(S[2][j], S[3][j]));
#pragma unroll
        for (int j = 0; j < 4; j++) {
            rmax[j] = fmaxf(rmax[j], __shfl_xor(rmax[j], 1));
            rmax[j] = fmaxf(rmax[j], __shfl_xor(rmax[j], 2));
            rmax[j] = fmaxf(rmax[j], __shfl_xor(rmax[j], 4));
            rmax[j] = fmaxf(rmax[j], __shfl_xor(rmax[j], 8));
        }
#pragma unroll
        for (int j = 0; j < 4; j++) {
            float mn = fmaxf(mrow[j], rmax[j]);
            alpha[j] = exp2f(mrow[j] - mn);
            mrow[j] = mn;
        }
#pragma unroll
        for (int ct = 0; ct < 4; ct++)
#pragma unroll
            for (int j = 0; j < 4; j++)
                S[ct][j] = exp2f(S[ct][j] - mrow[j]);
#pragma unroll
        for (int j = 0; j < 4; j++) {
            rsum[j] = S[0][j] + S[1][j] + S[2][j] + S[3][j];
            rsum[j] += __shfl_xor(rsum[j], 1);
            rsum[j] += __shfl_xor(rsum[j], 2);
            rsum[j] += __shfl_xor(rsum[j], 4);
            rsum[j] += __shfl_xor(rsum[j], 8);
            lrow[j] = lrow[j] * alpha[j] + rsum[j];
        }
        // P -> per-wave LDS (swizzled store), C-layout -> A-layout round trip
#pragma unroll
        for (int ct = 0; ct < 4; ct++)
#pragma unroll
            for (int j = 0; j < 4; j++) {
                const int prow = kg * 4 + j;
                const int pcol = ct * 16 + r16;
                pw[prow * 64 + (pcol ^ ((prow & 7) << 3))] = __float2bfloat16(S[ct][j]);
            }
#pragma unroll
        for (int ot = 0; ot < 4; ot++)
#pragma unroll
            for (int j = 0; j < 4; j++)
                O[ot][j] *= alpha[j];
#pragma unroll
        for (int ot = 0; ot < 4; ot++) {
            const int vr = ot * 16 + r16;
#pragma unroll
            for (int c = 0; c < 2; c++) {
                bf16x8 pa = *(const bf16x8*)(pw + r16 * 64 + ((c * 32 + kg * 8) ^ swr));
                bf16x8 vf = *(const bf16x8*)(Vlb + vr * 64 + ((c * 32 + kg * 8) ^ swr));
                O[ot] = __builtin_amdgcn_mfma_f32_16x16x32_bf16(pa, vf, O[ot], 0, 0, 0);
            }
        }
        __syncthreads();  // drains vmcnt(0): next buffer staged, this buffer free to overwrite
    }
    const int b = bh >> 4, h = bh & 15;
    float inv[4];
#pragma unroll
    for (int j = 0; j < 4; j++) inv[j] = 1.0f / lrow[j];
#pragma unroll
    for (int ot = 0; ot < 4; ot++)
#pragma unroll
        for (int j = 0; j < 4; j++) {
            int qq = qt * 64 + w * 16 + kg * 4 + j;
            y[((size_t)b * 2048 + qq) * 1024 + h * 64 + ot * 16 + r16] = __float2bfloat16(O[ot][j] * inv[j]);
        }
}

extern "C" void kernel_launch(void* const* d_in, const int* in_sizes, int n_in,
                              void* d_out, int out_size, void* d_ws, size_t ws_size,
                              hipStream_t stream) {
    const float* xp = (const float*)d_in[0];
    const float* Wq = (const float*)d_in[1];
    const float* bq = (const float*)d_in[2];
    const float* Wk = (const float*)d_in[3];
    const float* bk = (const float*)d_in[4];
    const float* Wv = (const float*)d_in[5];
    const float* bv = (const float*)d_in[6];
    const float* Wp = (const float*)d_in[7];
    const float* bp = (const float*)d_in[8];
    float* out = (float*)d_out;

    char* ws = (char*)d_ws;
    __hip_bfloat16* xb     = (__hip_bfloat16*)(ws);                  //  4096*1152 bf16
    __hip_bfloat16* Wqkv_t = (__hip_bfloat16*)(ws + 9437184);        //  3072*1152 bf16 (B^T)
    __hip_bfloat16* Wp_t   = (__hip_bfloat16*)(ws + 16515072);       //  1024*1024 bf16 (B^T)
    __hip_bfloat16* qb     = (__hip_bfloat16*)(ws + 18612224);       //  [32][2048][64]
    __hip_bfloat16* kbv    = (__hip_bfloat16*)(ws + 27000832);       //  [32][2048][64]
    __hip_bfloat16* vtb    = (__hip_bfloat16*)(ws + 35389440);       //  [32][64][2048] (V^T)
    __hip_bfloat16* yb     = (__hip_bfloat16*)(ws + 43778048);       //  [4096][1024]

    k_cvt_bf16<<<2304, 256, 0, stream>>>(xp, xb, 589824);
    dim3 trg(1024 / 32, 1152 / 32);
    k_tr<<<trg, 256, 0, stream>>>(Wq, Wqkv_t + (size_t)0 * 1024 * 1152, 1152, 1024);
    k_tr<<<trg, 256, 0, stream>>>(Wk, Wqkv_t + (size_t)1 * 1024 * 1152, 1152, 1024);
    k_tr<<<trg, 256, 0, stream>>>(Wv, Wqkv_t + (size_t)2 * 1024 * 1152, 1152, 1024);
    dim3 trg2(1024 / 32, 1024 / 32);
    k_tr<<<trg2, 256, 0, stream>>>(Wp, Wp_t, 1024, 1024);

    dim3 g1(4096 / 128, 3072 / 128);
    k_gemm<0><<<g1, 256, 0, stream>>>(xb, Wqkv_t, 4096, 3072, 1152, bq, bk, bv, qb, kbv, vtb, nullptr);
    dim3 ga(2048 / 64, 32);
    k_attn<<<ga, 256, 0, stream>>>(qb, kbv, vtb, yb);
    dim3 g2(4096 / 128, 1024 / 128);
    k_gemm<1><<<g2, 256, 0, stream>>>(yb, Wp_t, 4096, 1024, 1024, bp, nullptr, nullptr,
                                      nullptr, nullptr, nullptr, out);
}

// Round 3
// 142.724 us; speedup vs baseline: 1.6912x; 1.4383x over previous
//
#include <hip/hip_runtime.h>
#include <hip/hip_bf16.h>

typedef __attribute__((ext_vector_type(8))) short bf16x8;
typedef __attribute__((ext_vector_type(4))) float f32x4;
typedef __attribute__((ext_vector_type(2))) unsigned int u32x2;

__device__ __forceinline__ void gload_lds16(const void* g, void* l) {
    __builtin_amdgcn_global_load_lds(
        (const __attribute__((address_space(1))) unsigned int*)g,
        (__attribute__((address_space(3))) unsigned int*)l, 16, 0, 0);
}

// ---------------- fp32 -> bf16 elementwise convert (8 elems/thread) ----------------
__global__ void k_cvt_bf16(const float* __restrict__ x, __hip_bfloat16* __restrict__ o, int n8) {
    int i = blockIdx.x * 256 + threadIdx.x;
    if (i >= n8) return;
    const float4* xp = (const float4*)(x + (size_t)i * 8);
    float4 a = xp[0], b = xp[1];
    union { __hip_bfloat16 h[8]; uint4 u; } tu;
    tu.h[0] = __float2bfloat16(a.x); tu.h[1] = __float2bfloat16(a.y);
    tu.h[2] = __float2bfloat16(a.z); tu.h[3] = __float2bfloat16(a.w);
    tu.h[4] = __float2bfloat16(b.x); tu.h[5] = __float2bfloat16(b.y);
    tu.h[6] = __float2bfloat16(b.z); tu.h[7] = __float2bfloat16(b.w);
    *(uint4*)(o + (size_t)i * 8) = tu.u;
}

// ---------------- transpose fp32 [K][N] -> bf16 [N][K] ----------------
__global__ void k_tr(const float* __restrict__ src, __hip_bfloat16* __restrict__ dst, int K, int N) {
    __shared__ float tile[32][33];
    int n0 = blockIdx.x * 32, k0 = blockIdx.y * 32;
    int tx = threadIdx.x & 31, ty = threadIdx.x >> 5;
#pragma unroll
    for (int i = 0; i < 4; i++)
        tile[ty + i * 8][tx] = src[(size_t)(k0 + ty + i * 8) * N + n0 + tx];
    __syncthreads();
#pragma unroll
    for (int i = 0; i < 4; i++)
        dst[(size_t)(n0 + ty + i * 8) * K + k0 + tx] = __float2bfloat16(tile[tx][ty + i * 8]);
}

// ---------------- bf16 GEMM: C[M][N] = A[M][K] * Bt[N][K]^T, 128x128 tile ----------------
#define QSCALE 0.18033688011111204f  /* (1/8) * log2(e) */

template <int EPI>
__global__ __launch_bounds__(256, 2) void k_gemm(
    const __hip_bfloat16* __restrict__ A, const __hip_bfloat16* __restrict__ Bt,
    int M, int N, int K,
    const float* __restrict__ b0, const float* __restrict__ b1, const float* __restrict__ b2,
    __hip_bfloat16* __restrict__ qb, __hip_bfloat16* __restrict__ kb, __hip_bfloat16* __restrict__ vb,
    float* __restrict__ outp)
{
    __shared__ __align__(16) __hip_bfloat16 As[128 * 64];
    __shared__ __align__(16) __hip_bfloat16 Bs[128 * 64];
    const int t = threadIdx.x;
    const int lane = t & 63, w = t >> 6;
    const int wr = w >> 1, wc = w & 1;
    const int r16 = lane & 15, kg = lane >> 4;
    const int m0 = blockIdx.x * 128, n0 = blockIdx.y * 128;
    f32x4 acc[4][4] = {};
    const int ksteps = K >> 6;
    for (int kt = 0; kt < ksteps; ++kt) {
        if (kt) __syncthreads();
        const int ks = kt * 64;
#pragma unroll
        for (int i = 0; i < 4; i++) {
            int ci = i * 256 + t;
            int row = ci >> 3, kc = (ci & 7) * 8;
            gload_lds16(A + (size_t)(m0 + row) * K + ks + kc, As + ci * 8);
        }
#pragma unroll
        for (int i = 0; i < 4; i++) {
            int ci = i * 256 + t;
            int row = ci >> 3, kc = (ci & 7) * 8;
            gload_lds16(Bt + (size_t)(n0 + row) * K + ks + kc, Bs + ci * 8);
        }
        __syncthreads();
#pragma unroll
        for (int c = 0; c < 2; c++) {
            bf16x8 af[4], bfr[4];
#pragma unroll
            for (int mi = 0; mi < 4; mi++)
                af[mi] = *(const bf16x8*)(As + (wr * 64 + mi * 16 + r16) * 64 + c * 32 + kg * 8);
#pragma unroll
            for (int ni = 0; ni < 4; ni++)
                bfr[ni] = *(const bf16x8*)(Bs + (wc * 64 + ni * 16 + r16) * 64 + c * 32 + kg * 8);
#pragma unroll
            for (int mi = 0; mi < 4; mi++)
#pragma unroll
                for (int ni = 0; ni < 4; ni++)
                    acc[mi][ni] = __builtin_amdgcn_mfma_f32_16x16x32_bf16(af[mi], bfr[ni], acc[mi][ni], 0, 0, 0);
        }
    }
#pragma unroll
    for (int mi = 0; mi < 4; mi++) {
#pragma unroll
        for (int ni = 0; ni < 4; ni++) {
#pragma unroll
            for (int j = 0; j < 4; j++) {
                int m = m0 + wr * 64 + mi * 16 + kg * 4 + j;
                int n = n0 + wc * 64 + ni * 16 + r16;
                float val = acc[mi][ni][j];
                if (EPI == 0) {
                    int proj = n >> 10, r = n & 1023;
                    int hh = r >> 6, dd = r & 63;
                    int bb = m >> 11, tt = m & 2047;
                    if (proj == 0) {
                        val = (val + b0[r]) * QSCALE;
                        qb[((size_t)(bb * 16 + hh) * 2048 + tt) * 64 + dd] = __float2bfloat16(val);
                    } else if (proj == 1) {
                        val += b1[r];
                        kb[((size_t)(bb * 16 + hh) * 2048 + tt) * 64 + dd] = __float2bfloat16(val);
                    } else {
                        val += b2[r];
                        vb[((size_t)(bb * 16 + hh) * 64 + dd) * 2048 + tt] = __float2bfloat16(val);
                    }
                } else {
                    outp[(size_t)m * N + n] = val + b0[n];
                }
            }
        }
    }
}

// ---------------- flash attention v3 ----------------
// - swapped QK^T: mfma(K,Q) -> lane holds S^T[k][q], q = r16 lane-local => in-register
//   row reduce + 2 shfl_xor(16,32) instead of 32 shuffles
// - defer-max (T13, THR=8): skip alpha gather + O rescale when max didn't grow
// - packed ds_write_b64 P writeback (swizzled), LDS round-trip to [q][k] A-layout for PV
// - load-balanced (qt,bh) mapping: co-resident blocks {g,g+256,g+512,g+768} have qt-sum 62
__global__ __launch_bounds__(256, 4) void k_attn(
    const __hip_bfloat16* __restrict__ qbuf,
    const __hip_bfloat16* __restrict__ kbuf,
    const __hip_bfloat16* __restrict__ vtbuf,
    __hip_bfloat16* __restrict__ y)
{
    __shared__ __align__(16) __hip_bfloat16 Kl[2][64 * 64];
    __shared__ __align__(16) __hip_bfloat16 Vl[2][64 * 64];
    __shared__ __align__(16) __hip_bfloat16 Pl[4 * 16 * 64];
    const int t = threadIdx.x, lane = t & 63, w = t >> 6;
    const int r16 = lane & 15, kg = lane >> 4;
    // balanced remap
    const int g = blockIdx.x;
    const int c4 = g >> 8, p = g & 255;
    const int bh = (p >> 5) * 4 + c4;
    const int rr = p & 31;
    const int qt = (c4 & 1) ? rr : 31 - rr;
    const int swr = (r16 & 7) << 3;  // XOR swizzle (elements)
    const int q0 = qt * 64 + w * 16;
    const __hip_bfloat16* qp = qbuf + ((size_t)bh * 2048 + q0) * 64;
    bf16x8 qf0 = *(const bf16x8*)(qp + r16 * 64 + kg * 8);
    bf16x8 qf1 = *(const bf16x8*)(qp + r16 * 64 + 32 + kg * 8);
    f32x4 O[4] = {};
    float m_s = -3.0e38f, l_s = 0.f;
    const __hip_bfloat16* kb = kbuf + (size_t)bh * 2048 * 64;
    const __hip_bfloat16* vb = vtbuf + (size_t)bh * 64 * 2048;
    __hip_bfloat16* pw = Pl + w * 16 * 64;

    const int ci0 = t, ci1 = 256 + t;
    const int kr0 = ci0 >> 3, sc0 = ((ci0 & 7) * 8) ^ ((kr0 & 7) << 3);
    const int kr1 = ci1 >> 3, sc1 = ((ci1 & 7) * 8) ^ ((kr1 & 7) << 3);

    // prologue: stage tile 0 into buffer 0
    gload_lds16(kb + (size_t)kr0 * 64 + sc0, &Kl[0][ci0 * 8]);
    gload_lds16(kb + (size_t)kr1 * 64 + sc1, &Kl[0][ci1 * 8]);
    gload_lds16(vb + (size_t)kr0 * 2048 + sc0, &Vl[0][ci0 * 8]);
    gload_lds16(vb + (size_t)kr1 * 2048 + sc1, &Vl[0][ci1 * 8]);
    __syncthreads();

    for (int kt = 0; kt <= qt; ++kt) {
        const int cur = kt & 1;
        if (kt < qt) {  // prefetch next tile; latency hides under this tile's compute
            const int kn = kt + 1;
            gload_lds16(kb + (size_t)kn * 4096 + (size_t)kr0 * 64 + sc0, &Kl[cur ^ 1][ci0 * 8]);
            gload_lds16(kb + (size_t)kn * 4096 + (size_t)kr1 * 64 + sc1, &Kl[cur ^ 1][ci1 * 8]);
            gload_lds16(vb + (size_t)kr0 * 2048 + kn * 64 + sc0, &Vl[cur ^ 1][ci0 * 8]);
            gload_lds16(vb + (size_t)kr1 * 2048 + kn * 64 + sc1, &Vl[cur ^ 1][ci1 * 8]);
        }
        const __hip_bfloat16* Klb = Kl[cur];
        const __hip_bfloat16* Vlb = Vl[cur];
        // swapped QK^T: lane (kg,r16) gets S[k=ct*16+kg*4+j][q=r16]
        f32x4 S[4];
#pragma unroll
        for (int ct = 0; ct < 4; ct++) {
            f32x4 s = {};
            const int r = ct * 16 + r16;
            bf16x8 kf0 = *(const bf16x8*)(Klb + r * 64 + ((kg * 8) ^ swr));
            s = __builtin_amdgcn_mfma_f32_16x16x32_bf16(kf0, qf0, s, 0, 0, 0);
            bf16x8 kf1 = *(const bf16x8*)(Klb + r * 64 + ((32 + kg * 8) ^ swr));
            s = __builtin_amdgcn_mfma_f32_16x16x32_bf16(kf1, qf1, s, 0, 0, 0);
            S[ct] = s;
        }
        if (kt == qt) {  // diagonal tile: causal mask (k_local > q_local)
#pragma unroll
            for (int ct = 0; ct < 4; ct++)
#pragma unroll
                for (int j = 0; j < 4; j++)
                    if (ct * 16 + kg * 4 + j > w * 16 + r16) S[ct][j] = -3.0e38f;
        }
        // row max: in-lane over 16 values + cross-kg reduce
        float rmax = S[0][0];
#pragma unroll
        for (int ct = 0; ct < 4; ct++)
#pragma unroll
            for (int j = 0; j < 4; j++) rmax = fmaxf(rmax, S[ct][j]);
        rmax = fmaxf(rmax, __shfl_xor(rmax, 16));
        rmax = fmaxf(rmax, __shfl_xor(rmax, 32));
        // defer-max: only rescale when the max actually grew past THR=8
        if (__any(rmax > m_s + 8.0f)) {
            float mn = fmaxf(m_s, rmax);
            float alpha_s = exp2f(m_s - mn);
            m_s = mn;
            l_s *= alpha_s;
#pragma unroll
            for (int j = 0; j < 4; j++) {
                float aj = __shfl(alpha_s, (lane & 48) | (kg * 4 + j));
#pragma unroll
                for (int ot = 0; ot < 4; ot++) O[ot][j] *= aj;
            }
        }
        float rsum = 0.f;
#pragma unroll
        for (int ct = 0; ct < 4; ct++)
#pragma unroll
            for (int j = 0; j < 4; j++) {
                S[ct][j] = exp2f(S[ct][j] - m_s);
                rsum += S[ct][j];
            }
        rsum += __shfl_xor(rsum, 16);
        rsum += __shfl_xor(rsum, 32);
        l_s += rsum;
        // P writeback: lane holds 4 consecutive k per ct at row q=r16 -> packed b64 stores
#pragma unroll
        for (int ct = 0; ct < 4; ct++) {
            union { __hip_bfloat16 h[4]; u32x2 u; } pk;
            pk.h[0] = __float2bfloat16(S[ct][0]);
            pk.h[1] = __float2bfloat16(S[ct][1]);
            pk.h[2] = __float2bfloat16(S[ct][2]);
            pk.h[3] = __float2bfloat16(S[ct][3]);
            const int col = (ct * 16 + kg * 4) ^ swr;
            *(u32x2*)(pw + r16 * 64 + col) = pk.u;
        }
        // PV: A = P[q][k] (LDS round-trip), B = V^T[d][k]
        bf16x8 pa0 = *(const bf16x8*)(pw + r16 * 64 + ((kg * 8) ^ swr));
        bf16x8 pa1 = *(const bf16x8*)(pw + r16 * 64 + ((32 + kg * 8) ^ swr));
#pragma unroll
        for (int ot = 0; ot < 4; ot++) {
            const int vr = ot * 16 + r16;
            bf16x8 vf0 = *(const bf16x8*)(Vlb + vr * 64 + ((kg * 8) ^ swr));
            O[ot] = __builtin_amdgcn_mfma_f32_16x16x32_bf16(pa0, vf0, O[ot], 0, 0, 0);
            bf16x8 vf1 = *(const bf16x8*)(Vlb + vr * 64 + ((32 + kg * 8) ^ swr));
            O[ot] = __builtin_amdgcn_mfma_f32_16x16x32_bf16(pa1, vf1, O[ot], 0, 0, 0);
        }
        __syncthreads();  // drains vmcnt(0): next buffer staged, this buffer free
    }
    const int b = bh >> 4, h = bh & 15;
    float linv = 1.0f / l_s;
#pragma unroll
    for (int j = 0; j < 4; j++) {
        float ij = __shfl(linv, (lane & 48) | (kg * 4 + j));
        int qq = qt * 64 + w * 16 + kg * 4 + j;
#pragma unroll
        for (int ot = 0; ot < 4; ot++)
            y[((size_t)b * 2048 + qq) * 1024 + h * 64 + ot * 16 + r16] = __float2bfloat16(O[ot][j] * ij);
    }
}

extern "C" void kernel_launch(void* const* d_in, const int* in_sizes, int n_in,
                              void* d_out, int out_size, void* d_ws, size_t ws_size,
                              hipStream_t stream) {
    const float* xp = (const float*)d_in[0];
    const float* Wq = (const float*)d_in[1];
    const float* bq = (const float*)d_in[2];
    const float* Wk = (const float*)d_in[3];
    const float* bk = (const float*)d_in[4];
    const float* Wv = (const float*)d_in[5];
    const float* bv = (const float*)d_in[6];
    const float* Wp = (const float*)d_in[7];
    const float* bp = (const float*)d_in[8];
    float* out = (float*)d_out;

    char* ws = (char*)d_ws;
    __hip_bfloat16* xb     = (__hip_bfloat16*)(ws);                  //  4096*1152 bf16
    __hip_bfloat16* Wqkv_t = (__hip_bfloat16*)(ws + 9437184);        //  3072*1152 bf16 (B^T)
    __hip_bfloat16* Wp_t   = (__hip_bfloat16*)(ws + 16515072);       //  1024*1024 bf16 (B^T)
    __hip_bfloat16* qb     = (__hip_bfloat16*)(ws + 18612224);       //  [32][2048][64]
    __hip_bfloat16* kbv    = (__hip_bfloat16*)(ws + 27000832);       //  [32][2048][64]
    __hip_bfloat16* vtb    = (__hip_bfloat16*)(ws + 35389440);       //  [32][64][2048] (V^T)
    __hip_bfloat16* yb     = (__hip_bfloat16*)(ws + 43778048);       //  [4096][1024]

    k_cvt_bf16<<<2304, 256, 0, stream>>>(xp, xb, 589824);
    dim3 trg(1024 / 32, 1152 / 32);
    k_tr<<<trg, 256, 0, stream>>>(Wq, Wqkv_t + (size_t)0 * 1024 * 1152, 1152, 1024);
    k_tr<<<trg, 256, 0, stream>>>(Wk, Wqkv_t + (size_t)1 * 1024 * 1152, 1152, 1024);
    k_tr<<<trg, 256, 0, stream>>>(Wv, Wqkv_t + (size_t)2 * 1024 * 1152, 1152, 1024);
    dim3 trg2(1024 / 32, 1024 / 32);
    k_tr<<<trg2, 256, 0, stream>>>(Wp, Wp_t, 1024, 1024);

    dim3 g1(4096 / 128, 3072 / 128);
    k_gemm<0><<<g1, 256, 0, stream>>>(xb, Wqkv_t, 4096, 3072, 1152, bq, bk, bv, qb, kbv, vtb, nullptr);
    k_attn<<<1024, 256, 0, stream>>>(qb, kbv, vtb, yb);
    dim3 g2(4096 / 128, 1024 / 128);
    k_gemm<1><<<g2, 256, 0, stream>>>(yb, Wp_t, 4096, 1024, 1024, bp, nullptr, nullptr,
                                      nullptr, nullptr, nullptr, out);
}